// Round 8
// baseline (224.011 us; speedup 1.0000x reference)
//
#include <hip/hip_runtime.h>

#define TSTEPS 512
#define BPB    4                  // batches per block (rows 0,4,8,12)
#define ROWB   256                // bytes per A row (128 k-slot capacity, 96 used)
#define ABYTES (16 * ROWB)        // 4096
#define KSTEPS 3                  // K = 96 (hf 64 | x hi/lo 8 | bias 1 | pad)

typedef short bf16x8 __attribute__((ext_vector_type(8)));
typedef float f32x4  __attribute__((ext_vector_type(4)));

__device__ __forceinline__ float fast_sigmoid(float x) {
    return __builtin_amdgcn_rcpf(1.0f + __expf(-x));
}
__device__ __forceinline__ float fast_tanh(float x) {
    return 1.0f - 2.0f * __builtin_amdgcn_rcpf(__expf(2.0f * x) + 1.0f);
}
__device__ __forceinline__ unsigned int f2bf(float f) {   // RTN-even
    unsigned int u = __builtin_bit_cast(unsigned int, f);
    return (u + 0x7FFFu + ((u >> 16) & 1u)) >> 16;
}
__device__ __forceinline__ float bf2f(unsigned int us) {
    return __builtin_bit_cast(float, us << 16);
}
__device__ __forceinline__ unsigned int split_pack(float f) {  // hi | lo<<16
    unsigned int hi = f2bf(f);
    unsigned int lo = f2bf(f - bf2f(hi));
    return hi | (lo << 16);
}

// Same verified math as rounds 6/7: gates = [hf bf16 (64) | x hi/lo (8) | 1 | pad] @ B,
// B rows = M = W_hr^T W_hh^T (projection composed), W_ih, bias.
// NEW vs round 7:
//  * BPB=4, grid=512 -> TWO independent blocks per CU (launch_bounds(256,2)).
//    Barrier-locked chains of the two blocks co-schedule on the CU's SIMDs:
//    one chain's ds/MFMA/trans latency is filled by the other's issue (m114).
//  * Batch bl lives at A-row bl*4 = rows {0,4,8,12} = the r=0 C-row of every
//    lane group -> nonlin phase is ONE iteration, zero masked lanes.
// Unused A rows stay zero (row-separable in MFMA -> harmless).
__global__ __launch_bounds__(256, 2) void lstm_mfma5_kernel(
    const float* __restrict__ x,      // [B, T, 4]
    const float* __restrict__ W_ih,   // [256, 4]
    const float* __restrict__ W_hh,   // [256, 49]
    const float* __restrict__ b_ih,   // [256]
    const float* __restrict__ b_hh,   // [256]
    const float* __restrict__ W_hr,   // [49, 64]
    const float* __restrict__ W_out,  // [49, 49]
    const float* __restrict__ b_out,  // [49]
    float* __restrict__ out)          // [B, 49]
{
    const int tid = threadIdx.x;
    const int w   = tid >> 6;
    const int l   = tid & 63;
    const int g4  = l >> 4;
    const int ln  = l & 15;
    const int b0  = blockIdx.x * BPB;

    __shared__ __align__(128) unsigned char Abuf[2 * ABYTES];
    __shared__ __align__(16)  float hf32[BPB][64];
    __shared__ float hproj[BPB][52];

    // ---------------- prologue ----------------
    for (int i = tid; i < (2 * ABYTES) / 4; i += 256)
        ((unsigned int*)Abuf)[i] = 0u;
    __syncthreads();

    // M[k][n] for this lane's 16 k-slots (k = s*32 + g4*8 + j, s=0,1) x 4 n-cols
    float Msum[4][16];
    #pragma unroll
    for (int t4 = 0; t4 < 4; ++t4)
        #pragma unroll
        for (int i = 0; i < 16; ++i) Msum[t4][i] = 0.0f;

    for (int p = 0; p < 49; ++p) {
        float wr[16];
        #pragma unroll
        for (int s = 0; s < 2; ++s)
            #pragma unroll
            for (int j = 0; j < 8; ++j)
                wr[s * 8 + j] = W_hr[p * 64 + s * 32 + g4 * 8 + j];
        #pragma unroll
        for (int t4 = 0; t4 < 4; ++t4) {
            const float whh = W_hh[(t4 * 64 + w * 16 + ln) * 49 + p];
            #pragma unroll
            for (int i = 0; i < 16; ++i) Msum[t4][i] += whh * wr[i];
        }
    }

    // Resident B fragments: Bf[gate][kstep]; element j = k-slot s*32+g4*8+j
    bf16x8 Bf[4][KSTEPS];
    union U { unsigned int d[4]; bf16x8 v; };
    #pragma unroll
    for (int t4 = 0; t4 < 4; ++t4) {
        #pragma unroll
        for (int s = 0; s < 2; ++s) {
            U u;
            #pragma unroll
            for (int jj = 0; jj < 4; ++jj) {
                const unsigned int e0 = f2bf(Msum[t4][s * 8 + 2 * jj]);
                const unsigned int e1 = f2bf(Msum[t4][s * 8 + 2 * jj + 1]);
                u.d[jj] = e0 | (e1 << 16);
            }
            Bf[t4][s] = u.v;
        }
        U u; u.d[0] = u.d[1] = u.d[2] = u.d[3] = 0u;
        const int n = t4 * 64 + w * 16 + ln;
        if (g4 == 0) {                         // slots 64..71: x hi/lo pairs
            #pragma unroll
            for (int c = 0; c < 4; ++c) {
                const unsigned int us = f2bf(W_ih[n * 4 + c]);
                u.d[c] = us | (us << 16);
            }
        } else if (g4 == 1) {                  // slot 72: bias
            u.d[0] = f2bf(b_ih[n] + b_hh[n]);
        }
        Bf[t4][2] = u.v;
    }

    // x FIFO: 16 duty lanes (4 batches x 4 comps), 4 per wave
    const bool xduty = ((tid & 15) == 0);
    int xbase = 0, xrowbyte = 0;
    float xw = 0.f, xn = 0.f;
    if (xduty) {
        const int v    = tid >> 4;          // 0..15
        const int bl   = v >> 2;            // local batch 0..3
        const int comp = v & 3;
        const int row  = bl * 4;            // perm(bl) -> rows {0,4,8,12}
        xbase    = (b0 + bl) * (TSTEPS * 4) + comp;
        xrowbyte = (row * ROWB + 128 + 4 * comp) ^ ((row & 7) << 4);
        *(unsigned int*)(Abuf + xrowbyte) = split_pack(x[xbase]);   // seed x_0
        xw = x[xbase + 4 * 1];
        xn = x[xbase + 4 * 2];
    }
    // constant-1 bias column (slot 72, byte 144) into both buffers, all rows
    if (tid < 32) {
        const int row = tid & 15, buf = tid >> 4;
        const int byte = (row * ROWB + 144) ^ ((row & 7) << 4);
        *(unsigned int*)(Abuf + buf * ABYTES + byte) = 0x3F80u;   // bf16(1.0)
    }
    __syncthreads();

    // Hoisted addresses
    int aoff[KSTEPS];
    #pragma unroll
    for (int s = 0; s < KSTEPS; ++s)
        aoff[s] = (ln * ROWB + s * 64 + g4 * 16) ^ ((ln & 7) << 4);
    const int wrow  = g4 * 4;               // this lane's valid C row (r=0)
    const int woff0 = (wrow * ROWB + 2 * (w * 16 + ln)) ^ ((wrow & 7) << 4);

    float cst = 0.f;
    float hffin = 0.f;
    int cur = 0;

    // ---------------- recurrence ----------------
    for (int t = 0; t < TSTEPS; ++t) {
        float xn2 = 0.0f;
        if (xduty) {
            const int tt = (t + 3 < TSTEPS) ? t + 3 : TSTEPS - 1;
            xn2 = x[xbase + 4 * tt];
        }

        const unsigned char* Ab = Abuf + cur * ABYTES;
        bf16x8 af[KSTEPS];
        #pragma unroll
        for (int s = 0; s < KSTEPS; ++s)
            af[s] = *(const bf16x8*)(Ab + aoff[s]);

        f32x4 aI = {0.f, 0.f, 0.f, 0.f}, aF = aI, aG = aI, aO = aI;
        #pragma unroll
        for (int s = 0; s < KSTEPS; ++s) {
            aI = __builtin_amdgcn_mfma_f32_16x16x32_bf16(af[s], Bf[0][s], aI, 0, 0, 0);
            aF = __builtin_amdgcn_mfma_f32_16x16x32_bf16(af[s], Bf[1][s], aF, 0, 0, 0);
            aG = __builtin_amdgcn_mfma_f32_16x16x32_bf16(af[s], Bf[2][s], aG, 0, 0, 0);
            aO = __builtin_amdgcn_mfma_f32_16x16x32_bf16(af[s], Bf[3][s], aO, 0, 0, 0);
        }

        unsigned char* An = Abuf + (cur ^ 1) * ABYTES;
        {
            const float gi = fast_sigmoid(aI[0]);
            const float gf = fast_sigmoid(aF[0]);
            const float gg = fast_tanh(aG[0]);
            const float go = fast_sigmoid(aO[0]);
            cst = gf * cst + gi * gg;
            const float hf = go * fast_tanh(cst);
            hffin = hf;
            *(unsigned short*)(An + woff0) = (unsigned short)f2bf(hf);
        }
        if (xduty)
            *(unsigned int*)(An + xrowbyte) = split_pack(xw);
        xw = xn; xn = xn2;

        __syncthreads();
        cur ^= 1;
    }

    // ---------------- epilogue (exact fp32 two-stage) ----------------
    // C row g4*4 -> local batch g4
    hf32[g4][w * 16 + ln] = hffin;
    __syncthreads();

    for (int idx = tid; idx < BPB * 49; idx += 256) {
        const int bb = idx / 49, q = idx - bb * 49;
        float s = 0.0f;
        #pragma unroll 8
        for (int h = 0; h < 64; ++h) s += hf32[bb][h] * W_hr[q * 64 + h];
        hproj[bb][q] = s;
    }
    __syncthreads();
    for (int idx = tid; idx < BPB * 49; idx += 256) {
        const int bb = idx / 49, q2 = idx - bb * 49;
        float s = b_out[q2];
        #pragma unroll 7
        for (int p = 0; p < 49; ++p) s += hproj[bb][p] * W_out[q2 * 49 + p];
        out[(b0 + bb) * 49 + q2] = s;
    }
}

extern "C" void kernel_launch(void* const* d_in, const int* in_sizes, int n_in,
                              void* d_out, int out_size, void* d_ws, size_t ws_size,
                              hipStream_t stream) {
    (void)in_sizes; (void)n_in; (void)d_ws; (void)ws_size; (void)out_size;
    const float* x     = (const float*)d_in[0];
    const float* W_ih  = (const float*)d_in[1];
    const float* W_hh  = (const float*)d_in[2];
    const float* b_ih  = (const float*)d_in[3];
    const float* b_hh  = (const float*)d_in[4];
    const float* W_hr  = (const float*)d_in[5];
    const float* W_out = (const float*)d_in[6];
    const float* b_out = (const float*)d_in[7];
    float* outp = (float*)d_out;

    lstm_mfma5_kernel<<<dim3(2048 / BPB), dim3(256), 0, stream>>>(
        x, W_ih, W_hh, b_ih, b_hh, W_hr, W_out, b_out, outp);
}